// Round 1
// baseline (2041.451 us; speedup 1.0000x reference)
//
#include <hip/hip_runtime.h>
#include <hip/hip_bf16.h>

#define BROWS 32768
#define TM 64
#define TN 64
#define TK 16

enum { POST_NONE = 0, POST_RELU = 1, POST_EXP = 2, POST_SIG = 3 };

// C[M,N] = post(A[M,K] @ Bw[K,N] + bias[N])
// M divisible by 64 (grid.y = M/64). N,K arbitrary (guarded).
template <int POST>
__global__ __launch_bounds__(256) void gemm_post(
    const float* __restrict__ A, const float* __restrict__ Bw,
    const float* __restrict__ bias, float* __restrict__ C,
    int N, int K, int lda, int ldc)
{
    __shared__ float As[TK][68];   // transposed A tile [k][m], padded (68: 16B-aligned rows, 2-way max conflicts)
    __shared__ float Bs[TK][TN];   // [k][n]

    const int t = threadIdx.x;
    const int row0 = blockIdx.y * TM;
    const int col0 = blockIdx.x * TN;

    // loader mapping
    const int a_r = t >> 2;          // 0..63 tile row
    const int a_c = (t & 3) * 4;     // k-quad 0,4,8,12
    const int b_r = t >> 4;          // 0..15 k-row
    const int b_c = (t & 15) * 4;    // 0..60 col quad

    // compute mapping: 16x16 threads, 4x4 micro-tile
    const int tx = t & 15;
    const int ty = t >> 4;

    float acc[4][4];
#pragma unroll
    for (int i = 0; i < 4; ++i)
#pragma unroll
        for (int j = 0; j < 4; ++j) acc[i][j] = 0.f;

    const float* Ap = A + (size_t)(row0 + a_r) * lda;

    for (int kt = 0; kt < K; kt += TK) {
        // ---- load A tile (rows always valid; guard k) ----
        const int ak = kt + a_c;
        float4 av;
        if (ak + 3 < K) {
            av = *(const float4*)(Ap + ak);
        } else {
            av.x = (ak + 0 < K) ? Ap[ak + 0] : 0.f;
            av.y = (ak + 1 < K) ? Ap[ak + 1] : 0.f;
            av.z = (ak + 2 < K) ? Ap[ak + 2] : 0.f;
            av.w = (ak + 3 < K) ? Ap[ak + 3] : 0.f;
        }
        // ---- load B tile (guard k and n) ----
        const int bk = kt + b_r;
        const int bc = col0 + b_c;
        float4 bv = make_float4(0.f, 0.f, 0.f, 0.f);
        if (bk < K) {
            const float* Bp = Bw + (size_t)bk * N + bc;
            if (bc + 3 < N) {
                bv = *(const float4*)Bp;
            } else {
                if (bc + 0 < N) bv.x = Bp[0];
                if (bc + 1 < N) bv.y = Bp[1];
                if (bc + 2 < N) bv.z = Bp[2];
                if (bc + 3 < N) bv.w = Bp[3];
            }
        }
        As[a_c + 0][a_r] = av.x;
        As[a_c + 1][a_r] = av.y;
        As[a_c + 2][a_r] = av.z;
        As[a_c + 3][a_r] = av.w;
        *(float4*)&Bs[b_r][b_c] = bv;
        __syncthreads();

#pragma unroll
        for (int k = 0; k < TK; ++k) {
            const float4 a4 = *(const float4*)&As[k][ty * 4];
            const float4 b4 = *(const float4*)&Bs[k][tx * 4];
            acc[0][0] += a4.x * b4.x; acc[0][1] += a4.x * b4.y; acc[0][2] += a4.x * b4.z; acc[0][3] += a4.x * b4.w;
            acc[1][0] += a4.y * b4.x; acc[1][1] += a4.y * b4.y; acc[1][2] += a4.y * b4.z; acc[1][3] += a4.y * b4.w;
            acc[2][0] += a4.z * b4.x; acc[2][1] += a4.z * b4.y; acc[2][2] += a4.z * b4.z; acc[2][3] += a4.z * b4.w;
            acc[3][0] += a4.w * b4.x; acc[3][1] += a4.w * b4.y; acc[3][2] += a4.w * b4.z; acc[3][3] += a4.w * b4.w;
        }
        __syncthreads();
    }

    const int crow = row0 + ty * 4;
    const int ccol = col0 + tx * 4;
#pragma unroll
    for (int i = 0; i < 4; ++i) {
        float* Cp = C + (size_t)(crow + i) * ldc;
#pragma unroll
        for (int j = 0; j < 4; ++j) {
            const int c = ccol + j;
            if (c < N) {
                float v = acc[i][j] + bias[c];
                if (POST == POST_RELU) v = v > 0.f ? v : 0.f;
                else if (POST == POST_EXP) v = expf(v);
                else if (POST == POST_SIG) v = 1.f / (1.f + expf(-v));
                Cp[c] = v;
            }
        }
    }
}

// one wave per row: a = softmax(h1@Wa + ba); cdf; idx = first n with u < cdf else 0
__global__ __launch_bounds__(256) void a_idx_kernel(
    const float* __restrict__ h1, const float* __restrict__ Wa,
    const float* __restrict__ ba, const float* __restrict__ u,
    float* __restrict__ a_out, int* __restrict__ idx_out)
{
    const int r = blockIdx.x * 4 + (threadIdx.x >> 6);
    const int lane = threadIdx.x & 63;
    const float* hrow = h1 + (size_t)r * 400;

    float acc0 = 0.f, acc1 = 0.f, acc2 = 0.f, acc3 = 0.f, acc4 = 0.f;
    for (int k = lane; k < 400; k += 64) {
        const float h = hrow[k];
        const float* w = Wa + k * 5;
        acc0 += h * w[0]; acc1 += h * w[1]; acc2 += h * w[2];
        acc3 += h * w[3]; acc4 += h * w[4];
    }
    for (int off = 32; off; off >>= 1) {
        acc0 += __shfl_down(acc0, off);
        acc1 += __shfl_down(acc1, off);
        acc2 += __shfl_down(acc2, off);
        acc3 += __shfl_down(acc3, off);
        acc4 += __shfl_down(acc4, off);
    }
    if (lane == 0) {
        float l[5] = {acc0 + ba[0], acc1 + ba[1], acc2 + ba[2], acc3 + ba[3], acc4 + ba[4]};
        float mx = l[0];
        for (int n = 1; n < 5; ++n) mx = l[n] > mx ? l[n] : mx;
        float e[5], s = 0.f;
        for (int n = 0; n < 5; ++n) { e[n] = expf(l[n] - mx); s += e[n]; }
        const float inv = 1.f / s;
        const float uu = u[r];
        float cdf = 0.f;
        int idx = 0, found = 0;
        for (int n = 0; n < 5; ++n) {
            const float a = e[n] * inv;
            a_out[(size_t)r * 5 + n] = a;
            cdf += a;
            if (!found && uu < cdf) { idx = n; found = 1; }
        }
        idx_out[r] = idx;
    }
}

// one wave per row: solve Q w = eps (LU, partial pivot), z = Q @ (eigen*w) + mu
__global__ __launch_bounds__(256) void solve_kernel(
    const float* __restrict__ mu_o, const float* __restrict__ q_o,
    const float* __restrict__ e_o, const int* __restrict__ idxv,
    const float* __restrict__ eps, float* __restrict__ z)
{
    __shared__ float LU[4][20][21];
    __shared__ float Qo[4][20][21];
    __shared__ float rhs[4][20];
    __shared__ float wv[4][20];
    __shared__ float ew[4][20];

    const int wsl = threadIdx.x >> 6;
    const int lane = threadIdx.x & 63;
    const int r = blockIdx.x * 4 + wsl;

    const int idx = idxv[r];
    const float* Qp = q_o + (size_t)r * 2000 + idx * 400;
    for (int e = lane; e < 400; e += 64) {
        const float v = Qp[e];
        const int ri = e / 20, ci = e - ri * 20;
        LU[wsl][ri][ci] = v;
        Qo[wsl][ri][ci] = v;
    }
    if (lane < 20) rhs[wsl][lane] = eps[(size_t)r * 20 + lane];
    __syncthreads();

    for (int k = 0; k < 20; ++k) {
        // argmax |LU[i][k]|, i in [k,20)
        float val = -1.f;
        int ii = k;
        if (lane >= k && lane < 20) { val = fabsf(LU[wsl][lane][k]); ii = lane; }
        for (int off = 32; off; off >>= 1) {
            const float ov = __shfl_down(val, off);
            const int oi = __shfl_down(ii, off);
            if (ov > val) { val = ov; ii = oi; }
        }
        const int piv = __shfl(ii, 0);
        if (piv != k) {
            if (lane < 20) {
                const float t1 = LU[wsl][k][lane], t2 = LU[wsl][piv][lane];
                LU[wsl][k][lane] = t2;
                LU[wsl][piv][lane] = t1;
            } else if (lane == 20) {
                const float t1 = rhs[wsl][k];
                rhs[wsl][k] = rhs[wsl][piv];
                rhs[wsl][piv] = t1;
            }
        }
        __syncthreads();
        const float pv = LU[wsl][k][k];
        if (lane > k && lane < 20) {
            const float m = LU[wsl][lane][k] / pv;
            for (int j = k + 1; j < 20; ++j)
                LU[wsl][lane][j] -= m * LU[wsl][k][j];
            rhs[wsl][lane] -= m * rhs[wsl][k];
        }
        __syncthreads();
    }

    // back-substitution
    for (int k = 19; k >= 0; --k) {
        const float wk = rhs[wsl][k] / LU[wsl][k][k];
        if (lane == 0) wv[wsl][k] = wk;
        if (lane < k) rhs[wsl][lane] -= LU[wsl][lane][k] * wk;
        __syncthreads();
    }

    if (lane < 20) {
        const float evl = e_o[(size_t)r * 100 + idx * 20 + lane];
        ew[wsl][lane] = evl * wv[wsl][lane];
    }
    __syncthreads();
    if (lane < 20) {
        float acc = mu_o[(size_t)r * 100 + idx * 20 + lane];
        for (int j = 0; j < 20; ++j)
            acc += Qo[wsl][lane][j] * ew[wsl][j];
        z[(size_t)r * 20 + lane] = acc;
    }
}

extern "C" void kernel_launch(void* const* d_in, const int* in_sizes, int n_in,
                              void* d_out, int out_size, void* d_ws, size_t ws_size,
                              hipStream_t stream)
{
    const float* x   = (const float*)d_in[0];
    const float* u   = (const float*)d_in[1];
    const float* eps = (const float*)d_in[2];
    const float* W1  = (const float*)d_in[3];
    const float* b1  = (const float*)d_in[4];
    const float* Wmu = (const float*)d_in[5];
    const float* bmu = (const float*)d_in[6];
    const float* WQ  = (const float*)d_in[7];
    const float* bQ  = (const float*)d_in[8];
    const float* Wa  = (const float*)d_in[9];
    const float* ba  = (const float*)d_in[10];
    const float* We  = (const float*)d_in[11];
    const float* be  = (const float*)d_in[12];
    const float* W3  = (const float*)d_in[13];
    const float* b3  = (const float*)d_in[14];
    const float* W4  = (const float*)d_in[15];
    const float* b4  = (const float*)d_in[16];

    float* out   = (float*)d_out;
    float* recon = out;                                  // [B,784]
    float* mu_o  = out + (size_t)BROWS * 784;            // [B,100]
    float* q_o   = mu_o + (size_t)BROWS * 100;           // [B,2000]
    float* a_o   = q_o + (size_t)BROWS * 2000;           // [B,5]
    float* e_o   = a_o + (size_t)BROWS * 5;              // [B,100]

    char* ws   = (char*)d_ws;
    float* h1  = (float*)ws;                                             // [B,400], reused as h3
    float* z   = (float*)(ws + (size_t)BROWS * 400 * 4);                 // [B,20]
    int* idx   = (int*)(ws + (size_t)BROWS * 400 * 4 + (size_t)BROWS * 20 * 4);

    const dim3 blk(256);
    const int my = BROWS / TM;  // 512

    // encode
    gemm_post<POST_RELU><<<dim3((400 + TN - 1) / TN, my), blk, 0, stream>>>(x, W1, b1, h1, 400, 784, 784, 400);
    gemm_post<POST_NONE><<<dim3((100 + TN - 1) / TN, my), blk, 0, stream>>>(h1, Wmu, bmu, mu_o, 100, 400, 400, 100);
    gemm_post<POST_EXP><<<dim3((2000 + TN - 1) / TN, my), blk, 0, stream>>>(h1, WQ, bQ, q_o, 2000, 400, 400, 2000);
    gemm_post<POST_EXP><<<dim3((100 + TN - 1) / TN, my), blk, 0, stream>>>(h1, We, be, e_o, 100, 400, 400, 100);
    a_idx_kernel<<<BROWS / 4, blk, 0, stream>>>(h1, Wa, ba, u, a_o, idx);
    // sample + var@eps + mu
    solve_kernel<<<BROWS / 4, blk, 0, stream>>>(mu_o, q_o, e_o, idx, eps, z);
    // decode (h3 overwrites h1 buffer)
    gemm_post<POST_RELU><<<dim3((400 + TN - 1) / TN, my), blk, 0, stream>>>(z, W3, b3, h1, 400, 20, 20, 400);
    gemm_post<POST_SIG><<<dim3((784 + TN - 1) / TN, my), blk, 0, stream>>>(h1, W4, b4, recon, 784, 400, 400, 784);
}

// Round 2
// 1410.623 us; speedup vs baseline: 1.4472x; 1.4472x over previous
//
#include <hip/hip_runtime.h>
#include <hip/hip_bf16.h>

#define BROWS 32768

typedef __attribute__((ext_vector_type(8))) short bf16x8;
typedef __attribute__((ext_vector_type(4))) float f32x4;

enum { POST_NONE = 0, POST_RELU = 1, POST_EXP = 2, POST_SIG = 3 };

__device__ __forceinline__ unsigned short bf16_rne(float v) {
    unsigned u = __builtin_bit_cast(unsigned, v);
    u += 0x7fffu + ((u >> 16) & 1u);
    return (unsigned short)(u >> 16);
}
__device__ __forceinline__ float bf16_to_f(unsigned short h) {
    unsigned u = ((unsigned)h) << 16;
    return __builtin_bit_cast(float, u);
}

// C[M,N] = post(A[M,K] @ Bw[K,N] + bias[N]), M % 128 == 0, N,K guarded.
// Split-bf16 MFMA: each operand decomposed into PL bf16 planes; passes with
// pa+pb <= PL-1 accumulate in fp32 AGPRs. PL=2 -> 3 passes (~2^-16 rel),
// PL=3 -> 6 passes (~2^-24 rel, fp32-equivalent noise).
template <int POST, int PL>
__global__ __launch_bounds__(256) void gemm_mfma_split(
    const float* __restrict__ A, const float* __restrict__ Bw,
    const float* __restrict__ bias, float* __restrict__ C,
    int N, int K, int lda, int ldc)
{
    // LDS: [plane][row(m or n)][k] bf16, row stride 40 (pad: 16B-aligned rows,
    // bank period 8 over 32 banks -> ~2-way conflicts = free)
    __shared__ __align__(16) unsigned short As[PL][128 * 40];
    __shared__ __align__(16) unsigned short Bs[PL][128 * 40];

    const int t = threadIdx.x;
    const int row0 = blockIdx.y * 128;
    const int col0 = blockIdx.x * 128;

    const int wv = t >> 6, lane = t & 63;
    const int wr = (wv & 1) * 64, wc = (wv >> 1) * 64;   // wave 64x64 sub-tile
    const int l15 = lane & 15, quad = lane >> 4;

    // staging mapping: A: thread -> (row, 16-wide k-strip); B: (col, 16-deep k-strip)
    const int am = t >> 1, ak0 = (t & 1) * 16;
    const int bn = t & 127, bk0 = (t >> 7) * 16;
    const float* Arow = A + (size_t)(row0 + am) * lda;
    const int bcol = col0 + bn;

    f32x4 acc[4][4] = {};

    for (int kt = 0; kt < K; kt += 32) {
        // ---- global loads ----
        float av[16];
        if (kt + 32 <= K) {
            const float4* Ap = (const float4*)(Arow + kt + ak0);
#pragma unroll
            for (int j = 0; j < 4; ++j) {
                float4 q = Ap[j];
                av[j * 4 + 0] = q.x; av[j * 4 + 1] = q.y;
                av[j * 4 + 2] = q.z; av[j * 4 + 3] = q.w;
            }
        } else {
#pragma unroll
            for (int i = 0; i < 16; ++i) {
                int k = kt + ak0 + i;
                av[i] = (k < K) ? Arow[k] : 0.f;
            }
        }
        float bv[16];
        if (bcol < N) {
#pragma unroll
            for (int i = 0; i < 16; ++i) {
                int k = kt + bk0 + i;
                bv[i] = (k < K) ? Bw[(size_t)k * N + bcol] : 0.f;
            }
        } else {
#pragma unroll
            for (int i = 0; i < 16; ++i) bv[i] = 0.f;
        }

        // ---- split into bf16 planes ----
        unsigned short asp[PL][16], bsp[PL][16];
#pragma unroll
        for (int i = 0; i < 16; ++i) {
            float v = av[i];
#pragma unroll
            for (int p = 0; p < PL - 1; ++p) {
                unsigned short h = bf16_rne(v);
                asp[p][i] = h;
                v -= bf16_to_f(h);
            }
            asp[PL - 1][i] = bf16_rne(v);
            float w = bv[i];
#pragma unroll
            for (int p = 0; p < PL - 1; ++p) {
                unsigned short h = bf16_rne(w);
                bsp[p][i] = h;
                w -= bf16_to_f(h);
            }
            bsp[PL - 1][i] = bf16_rne(w);
        }

        __syncthreads();   // protect LDS from previous iteration's readers
#pragma unroll
        for (int p = 0; p < PL; ++p) {
#pragma unroll
            for (int h = 0; h < 2; ++h) {
                uint4 pa, pb;
                pa.x = (unsigned)asp[p][h * 8 + 0] | ((unsigned)asp[p][h * 8 + 1] << 16);
                pa.y = (unsigned)asp[p][h * 8 + 2] | ((unsigned)asp[p][h * 8 + 3] << 16);
                pa.z = (unsigned)asp[p][h * 8 + 4] | ((unsigned)asp[p][h * 8 + 5] << 16);
                pa.w = (unsigned)asp[p][h * 8 + 6] | ((unsigned)asp[p][h * 8 + 7] << 16);
                *(uint4*)&As[p][am * 40 + ak0 + h * 8] = pa;
                pb.x = (unsigned)bsp[p][h * 8 + 0] | ((unsigned)bsp[p][h * 8 + 1] << 16);
                pb.y = (unsigned)bsp[p][h * 8 + 2] | ((unsigned)bsp[p][h * 8 + 3] << 16);
                pb.z = (unsigned)bsp[p][h * 8 + 4] | ((unsigned)bsp[p][h * 8 + 5] << 16);
                pb.w = (unsigned)bsp[p][h * 8 + 6] | ((unsigned)bsp[p][h * 8 + 7] << 16);
                *(uint4*)&Bs[p][bn * 40 + bk0 + h * 8] = pb;
            }
        }
        __syncthreads();

        // ---- fragments: A[m=l15][k=quad*8+j], B[k=quad*8+j][n=l15] ----
        bf16x8 af[PL][4], bfz[PL][4];
#pragma unroll
        for (int p = 0; p < PL; ++p)
#pragma unroll
            for (int i = 0; i < 4; ++i) {
                af[p][i]  = *(const bf16x8*)&As[p][(wr + i * 16 + l15) * 40 + quad * 8];
                bfz[p][i] = *(const bf16x8*)&Bs[p][(wc + i * 16 + l15) * 40 + quad * 8];
            }
#pragma unroll
        for (int pa = 0; pa < PL; ++pa)
#pragma unroll
            for (int pb = 0; pb < PL; ++pb) {
                if (pa + pb <= PL - 1) {
#pragma unroll
                    for (int mt = 0; mt < 4; ++mt)
#pragma unroll
                        for (int nt = 0; nt < 4; ++nt)
                            acc[mt][nt] = __builtin_amdgcn_mfma_f32_16x16x32_bf16(
                                af[pa][mt], bfz[pb][nt], acc[mt][nt], 0, 0, 0);
                }
            }
    }

    // ---- epilogue: C/D map col=l15, row=quad*4+reg ----
#pragma unroll
    for (int nt = 0; nt < 4; ++nt) {
        const int col = col0 + wc + nt * 16 + l15;
        if (col < N) {
            const float bval = bias[col];
#pragma unroll
            for (int mt = 0; mt < 4; ++mt) {
                const int rbase = row0 + wr + mt * 16 + quad * 4;
#pragma unroll
                for (int r = 0; r < 4; ++r) {
                    float v = acc[mt][nt][r] + bval;
                    if (POST == POST_RELU) v = v > 0.f ? v : 0.f;
                    else if (POST == POST_EXP) v = expf(v);
                    else if (POST == POST_SIG) v = 1.f / (1.f + expf(-v));
                    C[(size_t)(rbase + r) * ldc + col] = v;
                }
            }
        }
    }
}

// one wave per row: a = softmax(h1@Wa + ba) in exact fp32; idx via inverse CDF
__global__ __launch_bounds__(256) void a_idx_kernel(
    const float* __restrict__ h1, const float* __restrict__ Wa,
    const float* __restrict__ ba, const float* __restrict__ u,
    float* __restrict__ a_out, int* __restrict__ idx_out)
{
    const int r = blockIdx.x * 4 + (threadIdx.x >> 6);
    const int lane = threadIdx.x & 63;
    const float* hrow = h1 + (size_t)r * 400;

    float acc0 = 0.f, acc1 = 0.f, acc2 = 0.f, acc3 = 0.f, acc4 = 0.f;
    for (int k = lane; k < 400; k += 64) {
        const float h = hrow[k];
        const float* w = Wa + k * 5;
        acc0 += h * w[0]; acc1 += h * w[1]; acc2 += h * w[2];
        acc3 += h * w[3]; acc4 += h * w[4];
    }
    for (int off = 32; off; off >>= 1) {
        acc0 += __shfl_down(acc0, off);
        acc1 += __shfl_down(acc1, off);
        acc2 += __shfl_down(acc2, off);
        acc3 += __shfl_down(acc3, off);
        acc4 += __shfl_down(acc4, off);
    }
    if (lane == 0) {
        float l[5] = {acc0 + ba[0], acc1 + ba[1], acc2 + ba[2], acc3 + ba[3], acc4 + ba[4]};
        float mx = l[0];
        for (int n = 1; n < 5; ++n) mx = l[n] > mx ? l[n] : mx;
        float e[5], s = 0.f;
        for (int n = 0; n < 5; ++n) { e[n] = expf(l[n] - mx); s += e[n]; }
        const float inv = 1.f / s;
        const float uu = u[r];
        float cdf = 0.f;
        int idx = 0, found = 0;
        for (int n = 0; n < 5; ++n) {
            const float a = e[n] * inv;
            a_out[(size_t)r * 5 + n] = a;
            cdf += a;
            if (!found && uu < cdf) { idx = n; found = 1; }
        }
        idx_out[r] = idx;
    }
}

// one wave per row: solve Q w = eps (LU, partial pivot), z = Q @ (eigen*w) + mu
__global__ __launch_bounds__(256) void solve_kernel(
    const float* __restrict__ mu_o, const float* __restrict__ q_o,
    const float* __restrict__ e_o, const int* __restrict__ idxv,
    const float* __restrict__ eps, float* __restrict__ z)
{
    __shared__ float LU[4][20][21];
    __shared__ float Qo[4][20][21];
    __shared__ float rhs[4][20];
    __shared__ float wv[4][20];
    __shared__ float ew[4][20];

    const int wsl = threadIdx.x >> 6;
    const int lane = threadIdx.x & 63;
    const int r = blockIdx.x * 4 + wsl;

    const int idx = idxv[r];
    const float* Qp = q_o + (size_t)r * 2000 + idx * 400;
    for (int e = lane; e < 400; e += 64) {
        const float v = Qp[e];
        const int ri = e / 20, ci = e - ri * 20;
        LU[wsl][ri][ci] = v;
        Qo[wsl][ri][ci] = v;
    }
    if (lane < 20) rhs[wsl][lane] = eps[(size_t)r * 20 + lane];
    __syncthreads();

    for (int k = 0; k < 20; ++k) {
        float val = -1.f;
        int ii = k;
        if (lane >= k && lane < 20) { val = fabsf(LU[wsl][lane][k]); ii = lane; }
        for (int off = 32; off; off >>= 1) {
            const float ov = __shfl_down(val, off);
            const int oi = __shfl_down(ii, off);
            if (ov > val) { val = ov; ii = oi; }
        }
        const int piv = __shfl(ii, 0);
        if (piv != k) {
            if (lane < 20) {
                const float t1 = LU[wsl][k][lane], t2 = LU[wsl][piv][lane];
                LU[wsl][k][lane] = t2;
                LU[wsl][piv][lane] = t1;
            } else if (lane == 20) {
                const float t1 = rhs[wsl][k];
                rhs[wsl][k] = rhs[wsl][piv];
                rhs[wsl][piv] = t1;
            }
        }
        __syncthreads();
        const float pv = LU[wsl][k][k];
        if (lane > k && lane < 20) {
            const float m = LU[wsl][lane][k] / pv;
            for (int j = k + 1; j < 20; ++j)
                LU[wsl][lane][j] -= m * LU[wsl][k][j];
            rhs[wsl][lane] -= m * rhs[wsl][k];
        }
        __syncthreads();
    }

    for (int k = 19; k >= 0; --k) {
        const float wk = rhs[wsl][k] / LU[wsl][k][k];
        if (lane == 0) wv[wsl][k] = wk;
        if (lane < k) rhs[wsl][lane] -= LU[wsl][lane][k] * wk;
        __syncthreads();
    }

    if (lane < 20) {
        const float evl = e_o[(size_t)r * 100 + idx * 20 + lane];
        ew[wsl][lane] = evl * wv[wsl][lane];
    }
    __syncthreads();
    if (lane < 20) {
        float acc = mu_o[(size_t)r * 100 + idx * 20 + lane];
        for (int j = 0; j < 20; ++j)
            acc += Qo[wsl][lane][j] * ew[wsl][j];
        z[(size_t)r * 20 + lane] = acc;
    }
}

extern "C" void kernel_launch(void* const* d_in, const int* in_sizes, int n_in,
                              void* d_out, int out_size, void* d_ws, size_t ws_size,
                              hipStream_t stream)
{
    const float* x   = (const float*)d_in[0];
    const float* u   = (const float*)d_in[1];
    const float* eps = (const float*)d_in[2];
    const float* W1  = (const float*)d_in[3];
    const float* b1  = (const float*)d_in[4];
    const float* Wmu = (const float*)d_in[5];
    const float* bmu = (const float*)d_in[6];
    const float* WQ  = (const float*)d_in[7];
    const float* bQ  = (const float*)d_in[8];
    const float* Wa  = (const float*)d_in[9];
    const float* ba  = (const float*)d_in[10];
    const float* We  = (const float*)d_in[11];
    const float* be  = (const float*)d_in[12];
    const float* W3  = (const float*)d_in[13];
    const float* b3  = (const float*)d_in[14];
    const float* W4  = (const float*)d_in[15];
    const float* b4  = (const float*)d_in[16];

    float* out   = (float*)d_out;
    float* recon = out;                                  // [B,784]
    float* mu_o  = out + (size_t)BROWS * 784;            // [B,100]
    float* q_o   = mu_o + (size_t)BROWS * 100;           // [B,2000]
    float* a_o   = q_o + (size_t)BROWS * 2000;           // [B,5]
    float* e_o   = a_o + (size_t)BROWS * 5;              // [B,100]

    char* ws   = (char*)d_ws;
    float* h1  = (float*)ws;                                             // [B,400], reused as h3
    float* z   = (float*)(ws + (size_t)BROWS * 400 * 4);                 // [B,20]
    int* idx   = (int*)(ws + (size_t)BROWS * 400 * 4 + (size_t)BROWS * 20 * 4);

    const dim3 blk(256);
    const int my = BROWS / 128;  // 256

    // encode: h1 via triple-split (fp32-equivalent noise -> idx stability)
    gemm_mfma_split<POST_RELU, 3><<<dim3(4, my), blk, 0, stream>>>(x, W1, b1, h1, 400, 784, 784, 400);
    gemm_mfma_split<POST_NONE, 2><<<dim3(1, my), blk, 0, stream>>>(h1, Wmu, bmu, mu_o, 100, 400, 400, 100);
    gemm_mfma_split<POST_EXP, 2><<<dim3(16, my), blk, 0, stream>>>(h1, WQ, bQ, q_o, 2000, 400, 400, 2000);
    gemm_mfma_split<POST_EXP, 2><<<dim3(1, my), blk, 0, stream>>>(h1, We, be, e_o, 100, 400, 400, 100);
    a_idx_kernel<<<BROWS / 4, blk, 0, stream>>>(h1, Wa, ba, u, a_o, idx);
    solve_kernel<<<BROWS / 4, blk, 0, stream>>>(mu_o, q_o, e_o, idx, eps, z);
    // decode
    gemm_mfma_split<POST_RELU, 2><<<dim3(4, my), blk, 0, stream>>>(z, W3, b3, h1, 400, 20, 20, 400);
    gemm_mfma_split<POST_SIG, 2><<<dim3(7, my), blk, 0, stream>>>(h1, W4, b4, recon, 784, 400, 400, 784);
}